// Round 8
// baseline (186.271 us; speedup 1.0000x reference)
//
#include <hip/hip_runtime.h>
#include <stdint.h>

// Problem dims (fixed by the reference)
#define NB   8192
#define NZ   10
#define CIN  512
#define COUT 512
#define MM   3
#define ALPHA 0.04419417382415922f   // 1/sqrt(512)

#define ROWS_TOTAL (NB * MM)          // 24576 GEMM rows (pos,d) d-fastest
#define BM 128
#define BN 128
#define BK 32
#define KITERS (CIN / BK)             // 16
#define MAX_MT (ROWS_TOTAL / BM + NZ) // 202
#define NYB (COUT / BN)               // 4
#define NWG (MAX_MT * NYB)            // 808, divisible by 8 (T1 swizzle)
#define NGRP 32                       // histogram groups of 256 nodes

typedef short bf16x8 __attribute__((ext_vector_type(8)));
typedef float f32x4  __attribute__((ext_vector_type(4)));

__device__ __forceinline__ uint16_t f2bf(float f) {
    union { float f; uint32_t i; } v; v.f = f;
    uint32_t x = v.i;
    x += 0x7fffu + ((x >> 16) & 1u);   // RNE
    return (uint16_t)(x >> 16);
}
__device__ __forceinline__ uint32_t pack2(float a, float b) {
    return (uint32_t)f2bf(a) | ((uint32_t)f2bf(b) << 16);
}
__device__ __forceinline__ void async16(const void* g, void* l) {
    __builtin_amdgcn_global_load_lds((const uint32_t*)g, (uint32_t*)l, 16, 0, 0);
}

// ---- K0: blocks 0..31 decode species + per-group histogram;
//          blocks 32..1311 pack W fp32->bf16 (lane-contiguous) -------------
__global__ __launch_bounds__(256)
void prep_kernel(const float* __restrict__ attrs, const float* __restrict__ w,
                 int* __restrict__ species, int* __restrict__ hist,
                 ushort* __restrict__ wt) {
    const int tid = threadIdx.x;
    if (blockIdx.x >= NGRP) {
        const size_t base = (size_t)(blockIdx.x - NGRP) * 2048;
        const float* src = w + base;
        ushort* dst = wt + base;
        float4 a = *(const float4*)(src + tid * 4);
        float4 b = *(const float4*)(src + 1024 + tid * 4);
        uint2 oa, ob;
        oa.x = pack2(a.x, a.y); oa.y = pack2(a.z, a.w);
        ob.x = pack2(b.x, b.y); ob.y = pack2(b.z, b.w);
        *(uint2*)(dst + tid * 4) = oa;
        *(uint2*)(dst + 1024 + tid * 4) = ob;
        return;
    }
    __shared__ int wc[4][NZ];
    const int b = blockIdx.x * 256 + tid;
    const float* a = attrs + (size_t)b * NZ;
    int s = 0;
    #pragma unroll
    for (int z = 0; z < NZ; z++) if (a[z] > 0.5f) s = z;
    species[b] = s;
    const int wv = tid >> 6, lane = tid & 63;
    #pragma unroll
    for (int z = 0; z < NZ; z++) {
        unsigned long long m = __ballot(s == z);
        if (lane == 0) wc[wv][z] = __popcll(m);
    }
    __syncthreads();
    if (tid < NZ) {
        hist[blockIdx.x * NZ + tid] = wc[0][tid] + wc[1][tid] + wc[2][tid] + wc[3][tid];
    }
}

// ---- K1: place (deterministic, atomic-free). 32 blocks x 256.
__global__ __launch_bounds__(256)
void place_kernel(const int* __restrict__ species, const int* __restrict__ hist,
                  int* __restrict__ sorted, int* __restrict__ offsets,
                  int* __restrict__ tile_offsets) {
    __shared__ int lhist[NGRP][NZ];
    __shared__ int loff[NZ + 1], ltoff[NZ + 1];
    __shared__ int pb[NZ];
    __shared__ int wc[4][NZ];
    const int tid = threadIdx.x, g = blockIdx.x;

    for (int i = tid; i < NGRP * NZ; i += 256) ((int*)lhist)[i] = hist[i];
    __syncthreads();
    if (tid == 0) {
        int off = 0, toff = 0;
        for (int z = 0; z < NZ; z++) {
            int tot = 0;
            for (int gg = 0; gg < NGRP; gg++) tot += lhist[gg][z];
            loff[z] = off; ltoff[z] = toff;
            off += tot;
            toff += (3 * tot + BM - 1) / BM;
        }
        loff[NZ] = off; ltoff[NZ] = toff;
    }
    __syncthreads();
    if (tid < NZ) {
        int base = loff[tid];
        for (int gg = 0; gg < g; gg++) base += lhist[gg][tid];
        pb[tid] = base;
    }
    if (g == 0 && tid < NZ + 1) {
        offsets[tid] = loff[tid];
        tile_offsets[tid] = ltoff[tid];
    }
    const int b = g * 256 + tid;
    const int s = species[b];
    const int wv = tid >> 6, lane = tid & 63;
    unsigned long long mymask = 0;
    #pragma unroll
    for (int z = 0; z < NZ; z++) {
        unsigned long long m = __ballot(s == z);
        if (lane == 0) wc[wv][z] = __popcll(m);
        if (s == z) mymask = m;
    }
    __syncthreads();
    int rank = __popcll(mymask & ((1ull << lane) - 1ull));
    #pragma unroll
    for (int w2 = 0; w2 < 4; w2++) if (w2 < wv) rank += wc[w2][s];
    sorted[pb[s] + rank] = b;
}

// ---- K2: pack t -> tt bf16, sorted order, d-major rows --------------------
__global__ __launch_bounds__(256)
void pack_t(const float* __restrict__ t, const int* __restrict__ sorted,
            ushort* __restrict__ tt) {
    const int w = threadIdx.x >> 6, L = threadIdx.x & 63;
    const int p = blockIdx.x * 4 + w;
    const int node = sorted[p];
    const float4* src = (const float4*)(t + (size_t)node * (CIN * MM) + L * 24);
    float4 f[6];
    #pragma unroll
    for (int i = 0; i < 6; i++) f[i] = src[i];
    const float* v = (const float*)f;          // v[c_local*3 + d]
    #pragma unroll
    for (int d = 0; d < MM; d++) {
        uint4 o;
        o.x = pack2(v[d],      v[3 + d]);
        o.y = pack2(v[6 + d],  v[9 + d]);
        o.z = pack2(v[12 + d], v[15 + d]);
        o.w = pack2(v[18 + d], v[21 + d]);
        *(uint4*)&tt[(size_t)(3 * p + d) * CIN + L * 8] = o;
    }
}

#define STAGE(bufi, ko) do {                                                 \
        async16(gA + (ko),            &smem[bufi][0][w * 32][0]);            \
        async16(gA + 16 * CIN + (ko), &smem[bufi][0][w * 32 + 16][0]);       \
        async16(gB + (ko),            &smem[bufi][1][w * 32][0]);            \
        async16(gB + 16 * CIN + (ko), &smem[bufi][1][w * 32 + 16][0]);       \
    } while (0)

// ---- K3: 128x128 MFMA GEMM (exact R5 structure, best measured) ------------
__global__ __launch_bounds__(256)
void gemm_kernel(const ushort* __restrict__ tt, const ushort* __restrict__ wt,
                 const int* __restrict__ sorted, const int* __restrict__ offsets,
                 const int* __restrict__ tile_offsets, float* __restrict__ out) {
    __shared__ __align__(16) ushort smem[3][2][BM][BK];
    __shared__ int spos[48];

    const int bid = blockIdx.x;
    const int nid = (bid & 7) * (NWG / 8) + (bid >> 3);
    const int tz = nid >> 2;
    const int Cbase = (nid & 3) * BN;

    if (tz >= tile_offsets[NZ]) return;
    int z = 0;
    #pragma unroll
    for (int i = 1; i < NZ; i++) if (tile_offsets[i] <= tz) z = i;

    const int row_base = 3 * offsets[z] + (tz - tile_offsets[z]) * BM;
    const int row_end  = 3 * offsets[z + 1];
    const int pos0     = row_base / 3;

    const int tid = threadIdx.x;
    const int w = tid >> 6, L = tid & 63;
    if (tid < 48) spos[tid] = sorted[min(pos0 + tid, NB - 1)];

    const int lr = L >> 2;
    const int cs = (L & 3) ^ ((L >> 3) & 3);
    const int soff = lr * CIN + cs * 8;
    const ushort* gA = tt + (size_t)(row_base + w * 32) * CIN + soff;
    const ushort* gB = wt + ((size_t)z * COUT + Cbase + w * 32) * CIN + soff;

    const int wm = w & 1, wn = w >> 1;
    const int q = L >> 4, mr = L & 15;
    const int sr8 = (q ^ ((mr >> 1) & 3)) * 8;

    f32x4 acc[4][4];
    #pragma unroll
    for (int i = 0; i < 4; i++)
        #pragma unroll
        for (int j = 0; j < 4; j++) acc[i][j] = (f32x4){0.f, 0.f, 0.f, 0.f};

    STAGE(0, 0);
    STAGE(1, BK);
    int cur = 0, nxt = 2;
    for (int kt = 0; kt < KITERS; kt++) {
        if (kt + 1 < KITERS) {
            asm volatile("s_waitcnt vmcnt(4)" ::: "memory");
        } else {
            asm volatile("s_waitcnt vmcnt(0)" ::: "memory");
        }
        asm volatile("s_barrier" ::: "memory");

        if (kt + 2 < KITERS) STAGE(nxt, (kt + 2) * BK);

        bf16x8 af[4], bf[4];
        #pragma unroll
        for (int am = 0; am < 4; am++)
            af[am] = *(const bf16x8*)&smem[cur][0][wm * 64 + am * 16 + mr][sr8];
        #pragma unroll
        for (int bn = 0; bn < 4; bn++)
            bf[bn] = *(const bf16x8*)&smem[cur][1][wn * 64 + bn * 16 + mr][sr8];
        #pragma unroll
        for (int am = 0; am < 4; am++)
            #pragma unroll
            for (int bn = 0; bn < 4; bn++)
                acc[am][bn] = __builtin_amdgcn_mfma_f32_16x16x32_bf16(
                    af[am], bf[bn], acc[am][bn], 0, 0, 0);

        cur = (cur == 2) ? 0 : cur + 1;
        nxt = (nxt == 2) ? 0 : nxt + 1;
    }

    float* ebuf = (float*)smem;
    #pragma unroll
    for (int ch = 0; ch < 3; ch++) {
        __syncthreads();
        const int pbase = pos0 + ch * 16;
        #pragma unroll
        for (int am = 0; am < 4; am++) {
            #pragma unroll
            for (int r = 0; r < 4; r++) {
                const int Rg = row_base + wm * 64 + am * 16 + q * 4 + r;
                const int pos = Rg / 3;
                const int d = Rg - 3 * pos;
                const int lp = pos - pbase;
                if (lp >= 0 && lp < 16 && Rg < row_end) {
                    #pragma unroll
                    for (int bn = 0; bn < 4; bn++) {
                        const int c = wn * 64 + bn * 16 + mr;
                        ebuf[(lp * BN + c) * 3 + d] = ALPHA * acc[am][bn][r];
                    }
                }
            }
        }
        __syncthreads();
        #pragma unroll 4
        for (int j = 0; j < 24; j++) {
            const int idx = j * 256 + tid;
            const int lp  = idx / 384;
            const int o   = idx - lp * 384;
            const int pos = pbase + lp;
            const int d   = o % 3;
            const int row = 3 * pos + d;
            if (row >= row_base && row < row_base + BM && row < row_end) {
                const int node = spos[pos - pos0];
                out[(size_t)node * (COUT * MM) + Cbase * 3 + o] = ebuf[idx];
            }
        }
    }
}

// ==== R8 DIAGNOSTIC SHADOWS (write only to scratch=tt region, post-gemm) ===
// V1: staging skeleton only (STAGE + vmcnt + barrier), 2x32 iters -> dur≈2S.
__global__ __launch_bounds__(256)
void gemm_stage_only(const ushort* __restrict__ tt, const ushort* __restrict__ wt,
                     const int* __restrict__ offsets,
                     const int* __restrict__ tile_offsets,
                     float* __restrict__ scr) {
    __shared__ __align__(16) ushort smem[3][2][BM][BK];
    const int bid = blockIdx.x;
    const int nid = (bid & 7) * (NWG / 8) + (bid >> 3);
    const int tz = nid >> 2;
    const int Cbase = (nid & 3) * BN;
    if (tz >= tile_offsets[NZ]) return;
    int z = 0;
    #pragma unroll
    for (int i = 1; i < NZ; i++) if (tile_offsets[i] <= tz) z = i;
    const int row_base = 3 * offsets[z] + (tz - tile_offsets[z]) * BM;
    const int tid = threadIdx.x;
    const int w = tid >> 6, L = tid & 63;
    const int lr = L >> 2;
    const int cs = (L & 3) ^ ((L >> 3) & 3);
    const int soff = lr * CIN + cs * 8;
    const ushort* gA = tt + (size_t)(row_base + w * 32) * CIN + soff;
    const ushort* gB = wt + ((size_t)z * COUT + Cbase + w * 32) * CIN + soff;

    STAGE(0, 0);
    STAGE(1, BK);
    int nxt = 2;
    for (int kt = 0; kt < 2 * KITERS; kt++) {
        if (kt + 1 < 2 * KITERS) {
            asm volatile("s_waitcnt vmcnt(4)" ::: "memory");
        } else {
            asm volatile("s_waitcnt vmcnt(0)" ::: "memory");
        }
        asm volatile("s_barrier" ::: "memory");
        if (kt + 2 < 2 * KITERS) STAGE(nxt, ((kt + 2) & (KITERS - 1)) * BK);
        nxt = (nxt == 2) ? 0 : nxt + 1;
    }
    if (tid == 0) scr[bid] = ((volatile float*)smem)[0];   // keep live
}

// V2: compute skeleton only (barrier + ds_read + MFMA on resident LDS),
// 2x32 iters -> dur≈2C. No VMEM in loop (vmcnt asm kept for parity, no-op).
__global__ __launch_bounds__(256)
void gemm_compute_only(const int* __restrict__ tile_offsets,
                       float* __restrict__ scr) {
    __shared__ __align__(16) ushort smem[3][2][BM][BK];
    const int bid = blockIdx.x;
    const int nid = (bid & 7) * (NWG / 8) + (bid >> 3);
    const int tz = nid >> 2;
    if (tz >= tile_offsets[NZ]) return;
    const int tid = threadIdx.x;
    const int w = tid >> 6, L = tid & 63;
    const int wm = w & 1, wn = w >> 1;
    const int q = L >> 4, mr = L & 15;
    const int sr8 = (q ^ ((mr >> 1) & 3)) * 8;

    f32x4 acc[4][4];
    #pragma unroll
    for (int i = 0; i < 4; i++)
        #pragma unroll
        for (int j = 0; j < 4; j++) acc[i][j] = (f32x4){0.f, 0.f, 0.f, 0.f};

    int cur = 0;
    for (int kt = 0; kt < 2 * KITERS; kt++) {
        asm volatile("s_waitcnt vmcnt(0)" ::: "memory");   // parity (no-op)
        asm volatile("s_barrier" ::: "memory");
        bf16x8 af[4], bf[4];
        #pragma unroll
        for (int am = 0; am < 4; am++)
            af[am] = *(const bf16x8*)&smem[cur][0][wm * 64 + am * 16 + mr][sr8];
        #pragma unroll
        for (int bn = 0; bn < 4; bn++)
            bf[bn] = *(const bf16x8*)&smem[cur][1][wn * 64 + bn * 16 + mr][sr8];
        #pragma unroll
        for (int am = 0; am < 4; am++)
            #pragma unroll
            for (int bn = 0; bn < 4; bn++)
                acc[am][bn] = __builtin_amdgcn_mfma_f32_16x16x32_bf16(
                    af[am], bf[bn], acc[am][bn], 0, 0, 0);
        cur = (cur == 2) ? 0 : cur + 1;
    }
    float s = 0.f;
    #pragma unroll
    for (int i = 0; i < 4; i++)
        #pragma unroll
        for (int j = 0; j < 4; j++)
            s += acc[i][j][0] + acc[i][j][1] + acc[i][j][2] + acc[i][j][3];
    scr[(size_t)bid * 256 + tid] = s;   // keep acc live (rule #17)
}

extern "C" void kernel_launch(void* const* d_in, const int* in_sizes, int n_in,
                              void* d_out, int out_size, void* d_ws, size_t ws_size,
                              hipStream_t stream) {
    const float* t     = (const float*)d_in[0];   // [B, IN, 3]  fp32
    const float* attrs = (const float*)d_in[1];   // [B, Z]      fp32 one-hot
    const float* w     = (const float*)d_in[2];   // [Z, OUT, IN] fp32
    float* out = (float*)d_out;                   // [B, OUT, 3] fp32

    uint8_t* ws = (uint8_t*)d_ws;
    int* species      = (int*)ws;                  ws += NB * 4;
    int* sorted       = (int*)ws;                  ws += NB * 4;
    int* hist         = (int*)ws;                  ws += NGRP * NZ * 4;
    int* offsets      = (int*)ws;                  ws += 16 * 4;
    int* tile_offsets = (int*)ws;                  ws += 16 * 4;
    ws = (uint8_t*)(((uintptr_t)ws + 255) & ~(uintptr_t)255);
    ushort* wt = (ushort*)ws;                      ws += (size_t)NZ * COUT * CIN * 2;
    ushort* tt = (ushort*)ws;                      // ROWS_TOTAL+BM rows x CIN bf16

    hipLaunchKernelGGL(prep_kernel, dim3(NGRP + (NZ * COUT * CIN) / 2048), dim3(256),
                       0, stream, attrs, w, species, hist, wt);
    hipLaunchKernelGGL(place_kernel, dim3(NGRP), dim3(256), 0, stream,
                       species, hist, sorted, offsets, tile_offsets);
    hipLaunchKernelGGL(pack_t, dim3(NB / 4), dim3(256), 0, stream, t, sorted, tt);
    hipLaunchKernelGGL(gemm_kernel, dim3(NWG), dim3(256), 0, stream,
                       tt, wt, sorted, offsets, tile_offsets, out);

    // Diagnostic shadows: scribble on tt AFTER gemm consumed it (pack_t
    // rewrites tt next iteration; out is untouched).
    float* scr = (float*)tt;
    hipLaunchKernelGGL(gemm_stage_only, dim3(NWG), dim3(256), 0, stream,
                       tt, wt, offsets, tile_offsets, scr);
    hipLaunchKernelGGL(gemm_compute_only, dim3(NWG), dim3(256), 0, stream,
                       tile_offsets, scr);
}

// Round 9
// 149.909 us; speedup vs baseline: 1.2426x; 1.2426x over previous
//
#include <hip/hip_runtime.h>
#include <stdint.h>

// Problem dims (fixed by the reference)
#define NB   8192
#define NZ   10
#define CIN  512
#define COUT 512
#define MM   3
#define ALPHA 0.04419417382415922f   // 1/sqrt(512)

#define ROWS_TOTAL (NB * MM)          // 24576 GEMM rows (pos,d) d-fastest
#define BM 256
#define BN 256
#define BK 32
#define NKT (CIN / BK)                // 16 K-tiles
#define MAX_MT (ROWS_TOTAL / BM + NZ) // 106
#define NYB (COUT / BN)               // 2
#define NWG (MAX_MT * NYB)            // 212 blocks
#define NGRP 32                       // histogram groups of 256 nodes

typedef short bf16x8 __attribute__((ext_vector_type(8)));
typedef float f32x4  __attribute__((ext_vector_type(4)));

__device__ __forceinline__ uint16_t f2bf(float f) {
    union { float f; uint32_t i; } v; v.f = f;
    uint32_t x = v.i;
    x += 0x7fffu + ((x >> 16) & 1u);   // RNE
    return (uint16_t)(x >> 16);
}
__device__ __forceinline__ uint32_t pack2(float a, float b) {
    return (uint32_t)f2bf(a) | ((uint32_t)f2bf(b) << 16);
}
__device__ __forceinline__ void async16(const void* g, void* l) {
    __builtin_amdgcn_global_load_lds((const uint32_t*)g, (uint32_t*)l, 16, 0, 0);
}

// ---- K0: blocks 0..31 decode species + per-group histogram;
//          blocks 32..1311 pack W fp32->bf16 (lane-contiguous) -------------
__global__ __launch_bounds__(256)
void prep_kernel(const float* __restrict__ attrs, const float* __restrict__ w,
                 int* __restrict__ species, int* __restrict__ hist,
                 ushort* __restrict__ wt) {
    const int tid = threadIdx.x;
    if (blockIdx.x >= NGRP) {
        const size_t base = (size_t)(blockIdx.x - NGRP) * 2048;
        const float* src = w + base;
        ushort* dst = wt + base;
        float4 a = *(const float4*)(src + tid * 4);
        float4 b = *(const float4*)(src + 1024 + tid * 4);
        uint2 oa, ob;
        oa.x = pack2(a.x, a.y); oa.y = pack2(a.z, a.w);
        ob.x = pack2(b.x, b.y); ob.y = pack2(b.z, b.w);
        *(uint2*)(dst + tid * 4) = oa;
        *(uint2*)(dst + 1024 + tid * 4) = ob;
        return;
    }
    __shared__ int wc[4][NZ];
    const int b = blockIdx.x * 256 + tid;
    const float* a = attrs + (size_t)b * NZ;
    int s = 0;
    #pragma unroll
    for (int z = 0; z < NZ; z++) if (a[z] > 0.5f) s = z;
    species[b] = s;
    const int wv = tid >> 6, lane = tid & 63;
    #pragma unroll
    for (int z = 0; z < NZ; z++) {
        unsigned long long m = __ballot(s == z);
        if (lane == 0) wc[wv][z] = __popcll(m);
    }
    __syncthreads();
    if (tid < NZ) {
        hist[blockIdx.x * NZ + tid] = wc[0][tid] + wc[1][tid] + wc[2][tid] + wc[3][tid];
    }
}

// ---- K1: place (deterministic, atomic-free). 32 blocks x 256.
__global__ __launch_bounds__(256)
void place_kernel(const int* __restrict__ species, const int* __restrict__ hist,
                  int* __restrict__ sorted, int* __restrict__ offsets,
                  int* __restrict__ tile_offsets) {
    __shared__ int lhist[NGRP][NZ];
    __shared__ int loff[NZ + 1], ltoff[NZ + 1];
    __shared__ int pb[NZ];
    __shared__ int wc[4][NZ];
    const int tid = threadIdx.x, g = blockIdx.x;

    for (int i = tid; i < NGRP * NZ; i += 256) ((int*)lhist)[i] = hist[i];
    __syncthreads();
    if (tid == 0) {
        int off = 0, toff = 0;
        for (int z = 0; z < NZ; z++) {
            int tot = 0;
            for (int gg = 0; gg < NGRP; gg++) tot += lhist[gg][z];
            loff[z] = off; ltoff[z] = toff;
            off += tot;
            toff += (3 * tot + BM - 1) / BM;   // BM=256 tiles now
        }
        loff[NZ] = off; ltoff[NZ] = toff;
    }
    __syncthreads();
    if (tid < NZ) {
        int base = loff[tid];
        for (int gg = 0; gg < g; gg++) base += lhist[gg][tid];
        pb[tid] = base;
    }
    if (g == 0 && tid < NZ + 1) {
        offsets[tid] = loff[tid];
        tile_offsets[tid] = ltoff[tid];
    }
    const int b = g * 256 + tid;
    const int s = species[b];
    const int wv = tid >> 6, lane = tid & 63;
    unsigned long long mymask = 0;
    #pragma unroll
    for (int z = 0; z < NZ; z++) {
        unsigned long long m = __ballot(s == z);
        if (lane == 0) wc[wv][z] = __popcll(m);
        if (s == z) mymask = m;
    }
    __syncthreads();
    int rank = __popcll(mymask & ((1ull << lane) - 1ull));
    #pragma unroll
    for (int w2 = 0; w2 < 4; w2++) if (w2 < wv) rank += wc[w2][s];
    sorted[pb[s] + rank] = b;
}

// ---- K2: pack t -> tt bf16, sorted order, d-major rows --------------------
__global__ __launch_bounds__(256)
void pack_t(const float* __restrict__ t, const int* __restrict__ sorted,
            ushort* __restrict__ tt) {
    const int w = threadIdx.x >> 6, L = threadIdx.x & 63;
    const int p = blockIdx.x * 4 + w;
    const int node = sorted[p];
    const float4* src = (const float4*)(t + (size_t)node * (CIN * MM) + L * 24);
    float4 f[6];
    #pragma unroll
    for (int i = 0; i < 6; i++) f[i] = src[i];
    const float* v = (const float*)f;          // v[c_local*3 + d]
    #pragma unroll
    for (int d = 0; d < MM; d++) {
        uint4 o;
        o.x = pack2(v[d],      v[3 + d]);
        o.y = pack2(v[6 + d],  v[9 + d]);
        o.z = pack2(v[12 + d], v[15 + d]);
        o.w = pack2(v[18 + d], v[21 + d]);
        *(uint4*)&tt[(size_t)(3 * p + d) * CIN + L * 8] = o;
    }
}

// ---- K3: 256x256 8-wave phase-split MFMA GEMM -----------------------------
// R9: port of the proven 8-wave phase-split mechanisms (T3/T4/T5 regime,
// 16-MFMA clusters) onto the race-safe 3-ring skeleton (R5-proven ledger).
// Evidence: R8 ablation — stage-only 8us, compute-only 8us, coupled 45us.
//  * 8 waves (512 thr), wave tile 128x64, acc[8][4]; 2 phases per K-tile.
//  * 3-slot LDS ring (3 x 32KB, dynamic): stage tile kt+2 -> slot (kt+2)%3,
//    never a live slot => phase boundaries carry no correctness weight.
//  * per-wave vmcnt ledger: 4 loads/tile (A0,A1 in P0; B0,B1 in P1);
//    steady state 8 outstanding -> vmcnt(4) retires tile kt; last iter 0.
//  * setprio(1) around each 16-MFMA cluster (T5, pays in 8-wave phase-split).
//  * cs/qs source-swizzle (R4/R5-verified ~0 conflicts), full-line epilogue.
__global__ __launch_bounds__(512, 2)
void gemm_kernel(const ushort* __restrict__ tt, const ushort* __restrict__ wt,
                 const int* __restrict__ sorted, const int* __restrict__ offsets,
                 const int* __restrict__ tile_offsets, float* __restrict__ out) {
    extern __shared__ __align__(16) ushort smem[];   // [3][A 256x32 | B 256x32]
    __shared__ int spos[96];

    // m204 bijective XCD swizzle for NWG=212 (q=26, r=4), y-fastest decode
    const int bid = blockIdx.x;
    const int xcd = bid & 7, ii = bid >> 3;
    const int wg = (xcd < 4 ? xcd * 27 : 108 + (xcd - 4) * 26) + ii;
    const int tz = wg >> 1;
    const int Cbase = (wg & 1) * BN;

    if (tz >= tile_offsets[NZ]) return;
    int z = 0;
    #pragma unroll
    for (int i = 1; i < NZ; i++) if (tile_offsets[i] <= tz) z = i;

    const int row_base = 3 * offsets[z] + (tz - tile_offsets[z]) * BM;
    const int row_end  = 3 * offsets[z + 1];
    const int pos0     = row_base / 3;

    const int tid = threadIdx.x;
    const int w = tid >> 6, L = tid & 63;
    if (tid < 96) spos[tid] = sorted[min(pos0 + tid, NB - 1)];

    // staging: per gload_lds, wave w covers 16 rows (w*16 + L>>2), 1KB.
    // A = 2 instrs (rows 0-127 / 128-255), B = 2. Source carries the
    // chunk-XOR swizzle cs = (L&3) ^ ((L>>3)&3)  [= c ^ ((row>>1)&3)].
    const int lr16 = w * 16 + (L >> 2);
    const int cs   = (L & 3) ^ ((L >> 3) & 3);
    const size_t aoff = (size_t)(row_base + lr16) * CIN + cs * 8;
    const size_t boff = ((size_t)z * COUT + Cbase + lr16) * CIN + cs * 8;

#define ASLOT(s) (smem + (s) * 16384)
#define BSLOT(s) (smem + (s) * 16384 + 8192)
#define STAGE_A(s, kt) do {                                                  \
        async16(tt + aoff + (kt) * BK,                    ASLOT(s) + w * 512);          \
        async16(tt + aoff + (size_t)128 * CIN + (kt) * BK, ASLOT(s) + 4096 + w * 512);  \
    } while (0)
#define STAGE_B(s, kt) do {                                                  \
        async16(wt + boff + (kt) * BK,                    BSLOT(s) + w * 512);          \
        async16(wt + boff + (size_t)128 * CIN + (kt) * BK, BSLOT(s) + 4096 + w * 512);  \
    } while (0)

    // compute: 2M x 4N wave grid; wave tile 128 rows x 64 cols
    const int wm = w & 1, wn = w >> 1;
    const int q = L >> 4, mr = L & 15;
    const int qs = (q ^ ((mr >> 1) & 3)) * 8;   // swizzled k-chunk (elems)

    f32x4 acc[8][4];
    #pragma unroll
    for (int i = 0; i < 8; i++)
        #pragma unroll
        for (int j = 0; j < 4; j++) acc[i][j] = (f32x4){0.f, 0.f, 0.f, 0.f};

    // prologue: tiles 0 and 1 (per-wave FIFO: A,A,B,B per tile)
    STAGE_A(0, 0); STAGE_B(0, 0);
    STAGE_A(1, 1); STAGE_B(1, 1);

    int cur = 0, stg = 2;
    for (int kt = 0; kt < NKT; kt++) {
        // ---- P0: retire tile kt (own 4 oldest loads), sync, stage A(kt+2)
        if (kt + 1 < NKT) {
            asm volatile("s_waitcnt vmcnt(4)" ::: "memory");
        } else {
            asm volatile("s_waitcnt vmcnt(0)" ::: "memory");
        }
        asm volatile("s_barrier" ::: "memory");
        if (kt + 2 < NKT) STAGE_A(stg, kt + 2);

        const ushort* Ab = ASLOT(cur);
        const ushort* Bb = BSLOT(cur);
        bf16x8 af[4], bf[4];
        #pragma unroll
        for (int am = 0; am < 4; am++)
            af[am] = *(const bf16x8*)(Ab + (wm * 128 + am * 16 + mr) * 32 + qs);
        #pragma unroll
        for (int bn = 0; bn < 4; bn++)
            bf[bn] = *(const bf16x8*)(Bb + (wn * 64 + bn * 16 + mr) * 32 + qs);
        __builtin_amdgcn_s_setprio(1);
        #pragma unroll
        for (int am = 0; am < 4; am++)
            #pragma unroll
            for (int bn = 0; bn < 4; bn++)
                acc[am][bn] = __builtin_amdgcn_mfma_f32_16x16x32_bf16(
                    af[am], bf[bn], acc[am][bn], 0, 0, 0);
        __builtin_amdgcn_s_setprio(0);

        // ---- P1: pacing barrier, stage B(kt+2), second row-half MFMAs
        asm volatile("s_barrier" ::: "memory");
        if (kt + 2 < NKT) STAGE_B(stg, kt + 2);

        bf16x8 ag[4];
        #pragma unroll
        for (int am = 0; am < 4; am++)
            ag[am] = *(const bf16x8*)(Ab + (wm * 128 + (am + 4) * 16 + mr) * 32 + qs);
        __builtin_amdgcn_s_setprio(1);
        #pragma unroll
        for (int am = 0; am < 4; am++)
            #pragma unroll
            for (int bn = 0; bn < 4; bn++)
                acc[am + 4][bn] = __builtin_amdgcn_mfma_f32_16x16x32_bf16(
                    ag[am], bf[bn], acc[am + 4][bn], 0, 0, 0);
        __builtin_amdgcn_s_setprio(0);

        cur = (cur == 2) ? 0 : cur + 1;
        stg = (stg == 2) ? 0 : stg + 1;
    }
#undef STAGE_A
#undef STAGE_B

    // ---- epilogue: acc -> ebuf [16 pos][BN][3] -> full-line global stores
    float* ebuf = (float*)smem;          // 48 KB of the 96 KB ring
    #pragma unroll
    for (int ch = 0; ch < 6; ch++) {
        __syncthreads();                 // first iter: protects slot0 vs P1 readers
        const int pbase = pos0 + ch * 16;
        #pragma unroll
        for (int am = 0; am < 8; am++) {
            #pragma unroll
            for (int r = 0; r < 4; r++) {
                const int Rg = row_base + wm * 128 + am * 16 + q * 4 + r;
                const int pos = Rg / 3;
                const int d = Rg - 3 * pos;
                const int lp = pos - pbase;
                if (lp >= 0 && lp < 16 && Rg < row_end) {
                    #pragma unroll
                    for (int bn = 0; bn < 4; bn++) {
                        const int c = wn * 64 + bn * 16 + mr;
                        ebuf[(lp * BN + c) * 3 + d] = ALPHA * acc[am][bn][r];
                    }
                }
            }
        }
        __syncthreads();
        // 16 pos x 768 floats; per-pos 3072B contiguous at out[node]+Cbase*3
        #pragma unroll 4
        for (int j = 0; j < 24; j++) {
            const int idx = j * 512 + tid;           // 0..12287, lane-contiguous
            const int lp  = idx / 768;
            const int o   = idx - lp * 768;          // = c*3 + d
            const int pos = pbase + lp;
            const int d   = o % 3;
            const int row = 3 * pos + d;
            if (row >= row_base && row < row_base + BM && row < row_end) {
                const int node = spos[pos - pos0];
                out[(size_t)node * (COUT * MM) + Cbase * 3 + o] = ebuf[idx];
            }
        }
    }
}

extern "C" void kernel_launch(void* const* d_in, const int* in_sizes, int n_in,
                              void* d_out, int out_size, void* d_ws, size_t ws_size,
                              hipStream_t stream) {
    const float* t     = (const float*)d_in[0];   // [B, IN, 3]  fp32
    const float* attrs = (const float*)d_in[1];   // [B, Z]      fp32 one-hot
    const float* w     = (const float*)d_in[2];   // [Z, OUT, IN] fp32
    float* out = (float*)d_out;                   // [B, OUT, 3] fp32

    uint8_t* ws = (uint8_t*)d_ws;
    int* species      = (int*)ws;                  ws += NB * 4;
    int* sorted       = (int*)ws;                  ws += NB * 4;
    int* hist         = (int*)ws;                  ws += NGRP * NZ * 4;
    int* offsets      = (int*)ws;                  ws += 16 * 4;
    int* tile_offsets = (int*)ws;                  ws += 16 * 4;
    ws = (uint8_t*)(((uintptr_t)ws + 255) & ~(uintptr_t)255);
    ushort* wt = (ushort*)ws;                      ws += (size_t)NZ * COUT * CIN * 2;
    ushort* tt = (ushort*)ws;                      // (ROWS_TOTAL + BM) rows x CIN bf16

    hipLaunchKernelGGL(prep_kernel, dim3(NGRP + (NZ * COUT * CIN) / 2048), dim3(256),
                       0, stream, attrs, w, species, hist, wt);
    hipLaunchKernelGGL(place_kernel, dim3(NGRP), dim3(256), 0, stream,
                       species, hist, sorted, offsets, tile_offsets);
    hipLaunchKernelGGL(pack_t, dim3(NB / 4), dim3(256), 0, stream, t, sorted, tt);
    // 96 KB dynamic LDS (3-slot ring); 128 KB dynamic is m201-precedented on gfx950
    hipLaunchKernelGGL(gemm_kernel, dim3(NWG), dim3(512), 3 * 2 * 256 * BK * 2, stream,
                       tt, wt, sorted, offsets, tile_offsets, out);
}